// Round 15
// baseline (21533.060 us; speedup 1.0000x reference)
//
#include <hip/hip_runtime.h>

// RNN: B=32, T=2048, E=256, H=256, L=2, f32 in/out, f16 dot core.
// Pipeline (r8/r13-proven): proj0 -> ws.A; mega 128 blocks co-resident:
//   blk 0-31   L0 scan -> d_out rows; publish flagL0[b] every CHUNK steps
//   blk 32-95  chasers (2/batch): xproj1 = h0 @ W1x + b1 -> ws.A
//   blk 96-127 L1 scan: wait chunkdone -> d_out rows + final ht
//
// v15 = v14 with the LDS buffer size BUG FIXED: hb[2][16] (256B/buf) ->
// hb[2][32] (512B/buf = 256 f16). r14's double buffers aliased: tid>=128
// writes and hp4_[m>=16] reads spilled into the other buffer -> garbage h
// (absmax 1.94). Design unchanged:
// 256 thr/block, lane owns FULL column j=tid. 256-MAC dot via 128
// v_dot2_f32_f16 on packed-f16x2 weight VGPRs. h in LDS as f16; all lanes
// read the SAME addresses -> broadcast, conflict-free. NO reduce — z is
// lane-complete. launch_bounds(256,1): 512-reg budget, demand ~190 -> no
// AGPR parking (r13 keep-alive retained as insurance).
// Sync (r13-proven): publisher __syncthreads + release store; consumer
// RELAXED poll + one acquire fence per chunk. Scan barrier LDS-only.

typedef _Float16 half2_t __attribute__((ext_vector_type(2)));

#define TT 2048
#define BB 32
#define XPB 8
#define CHUNK 64
#define NCHUNK (TT / CHUNK)  // 32

__device__ __forceinline__ half2_t h2pack(float lo, float hi) {
    half2_t r;
    r.x = (_Float16)lo;
    r.y = (_Float16)hi;
    return r;
}

#define LDS_BARRIER() asm volatile("s_waitcnt lgkmcnt(0)\n\ts_barrier" ::: "memory")

__device__ __forceinline__ int rload(int* pf) {
    return __hip_atomic_load(pf, __ATOMIC_RELAXED, __HIP_MEMORY_SCOPE_AGENT);
}
__device__ __forceinline__ void astore(int* pf, int v) {
    __hip_atomic_store(pf, v, __ATOMIC_RELEASE, __HIP_MEMORY_SCOPE_AGENT);
}
#define ACQUIRE_FENCE() __builtin_amdgcn_fence(__ATOMIC_ACQUIRE, "agent")

// r13-proven keep-alive: force the 128 packed weights into arch VGPRs per step
#define KAW8(B)                                                           \
    "+v"(wp[(B)]), "+v"(wp[(B) + 1]), "+v"(wp[(B) + 2]), "+v"(wp[(B) + 3]), \
    "+v"(wp[(B) + 4]), "+v"(wp[(B) + 5]), "+v"(wp[(B) + 6]), "+v"(wp[(B) + 7])
#define KEEPALIVE()                                                  \
    asm volatile("" : KAW8(0), KAW8(8), KAW8(16), KAW8(24));         \
    asm volatile("" : KAW8(32), KAW8(40), KAW8(48), KAW8(56));       \
    asm volatile("" : KAW8(64), KAW8(72), KAW8(80), KAW8(88));       \
    asm volatile("" : KAW8(96), KAW8(104), KAW8(112), KAW8(120));

// full 256-MAC dot for this lane's column; HB = uint4* to 512B f16 h buffer
#define DOT256(HB, Z)                                                       \
    {                                                                       \
        const uint4* hp4_ = (const uint4*)(HB);                             \
        float ac0 = 0.f, ac1 = 0.f, ac2 = 0.f, ac3 = 0.f;                   \
        _Pragma("unroll")                                                   \
        for (int m = 0; m < 32; ++m) {                                      \
            uint4 r_ = hp4_[m];                                             \
            ac0 = __builtin_amdgcn_fdot2(__builtin_bit_cast(half2_t, r_.x), \
                                         wp[4 * m + 0], ac0, false);        \
            ac1 = __builtin_amdgcn_fdot2(__builtin_bit_cast(half2_t, r_.y), \
                                         wp[4 * m + 1], ac1, false);        \
            ac2 = __builtin_amdgcn_fdot2(__builtin_bit_cast(half2_t, r_.z), \
                                         wp[4 * m + 2], ac2, false);        \
            ac3 = __builtin_amdgcn_fdot2(__builtin_bit_cast(half2_t, r_.w), \
                                         wp[4 * m + 3], ac3, false);        \
        }                                                                   \
        Z = (ac0 + ac1) + (ac2 + ac3);                                      \
    }

// proj rows: out[r][j] = in[r][:] . W[:256][j] + b[j], rows staged f32->f16
// in double-buffered LDS. In-place safe: row-r write vs row-(r+1) read are
// disjoint, and the staged value is in LDS (drained by syncthreads) before
// its source row could be overwritten next iteration.
__device__ __forceinline__ void proj_rows(
    const float* __restrict__ src, float* __restrict__ dst,
    half2_t (&wp)[128], float bj, int nrows, uint4 (*hb)[32], int tid)
{
    _Float16* st0 = reinterpret_cast<_Float16*>(hb[0]);
    _Float16* st1 = reinterpret_cast<_Float16*>(hb[1]);
    st0[tid] = (_Float16)src[tid];
    __syncthreads();
    for (int r = 0; r < nrows; ++r) {
        _Float16* stn = (r & 1) ? st0 : st1;
        if (r + 1 < nrows) stn[tid] = (_Float16)src[(size_t)(r + 1) * 256 + tid];
        float z;
        DOT256(hb[r & 1], z);
        dst[(size_t)r * 256 + tid] = z + bj;
        __syncthreads();
    }
}

// MODE: 0 = serial, 1 = L0 (publish pubflag), 2 = L1 (wait waitflags)
template <int MODE>
__device__ __forceinline__ void scan_core(
    const float* __restrict__ W, const float* __restrict__ h_init,
    const float* __restrict__ xsrc, float* __restrict__ hdst, float* hfinal,
    int* pubflag, int* waitflags, uint4 (*hb)[32], int tid)
{
    const int j = tid;
    half2_t wp[128];
#pragma unroll 8
    for (int k = 0; k < 128; ++k) {
        float w0 = W[(size_t)(256 + 2 * k) * 256 + j];
        float w1 = W[(size_t)(256 + 2 * k + 1) * 256 + j];
        wp[k] = h2pack(w0, w1);
    }
    _Float16* hw0 = reinterpret_cast<_Float16*>(hb[0]);
    _Float16* hw1 = reinterpret_cast<_Float16*>(hb[1]);
    hw0[j] = (_Float16)h_init[j];

    float xpc[XPB], xpn[XPB], hs[XPB];

    auto step = [&](int t, float xp) -> float {
        KEEPALIVE()
        float z;
        DOT256(hb[t & 1], z);
        z += xp;
        const float e = __expf(2.0f * z);
        const float hn = 1.0f - 2.0f / (e + 1.0f);
        _Float16* dstw = ((t + 1) & 1) ? hw1 : hw0;
        dstw[j] = (_Float16)hn;
        LDS_BARRIER();
        return hn;
    };

    if (MODE != 2) {
#pragma unroll
        for (int u = 0; u < XPB; ++u) xpc[u] = xsrc[(size_t)u * 256 + j];
        __syncthreads();
        for (int t0 = 0; t0 < TT; t0 += XPB) {
            const bool more = (t0 + XPB) < TT;
            if (more) {
#pragma unroll
                for (int u = 0; u < XPB; ++u)
                    xpn[u] = xsrc[(size_t)(t0 + XPB + u) * 256 + j];
            }
#pragma unroll
            for (int u = 0; u < XPB; ++u) hs[u] = step(t0 + u, xpc[u]);
#pragma unroll
            for (int u = 0; u < XPB; ++u)
                hdst[(size_t)(t0 + u) * 256 + j] = hs[u];
            if (MODE == 1 && (((t0 + XPB) & (CHUNK - 1)) == 0)) {
                __syncthreads();  // drain vmcnt (h stores) before release
                if (tid == 0) astore(pubflag, t0 + XPB);
            }
            if (more) {
#pragma unroll
                for (int u = 0; u < XPB; ++u) xpc[u] = xpn[u];
            }
        }
        if (MODE == 0 && hfinal != nullptr) hfinal[j] = hs[XPB - 1];
    } else {
        __syncthreads();
        for (int chunk = 0; chunk < NCHUNK; ++chunk) {
            const int tbase = chunk * CHUNK;
            while (rload(&waitflags[chunk]) == 0) __builtin_amdgcn_s_sleep(1);
            ACQUIRE_FENCE();  // one inv per chunk
#pragma unroll
            for (int u = 0; u < XPB; ++u)
                xpc[u] = xsrc[(size_t)(tbase + u) * 256 + j];
            for (int g = 0; g < CHUNK / XPB; ++g) {
                const int t0 = tbase + g * XPB;
                if (g + 1 < CHUNK / XPB) {
#pragma unroll
                    for (int u = 0; u < XPB; ++u)
                        xpn[u] = xsrc[(size_t)(t0 + XPB + u) * 256 + j];
                }
#pragma unroll
                for (int u = 0; u < XPB; ++u) hs[u] = step(t0 + u, xpc[u]);
#pragma unroll
                for (int u = 0; u < XPB; ++u)
                    hdst[(size_t)(t0 + u) * 256 + j] = hs[u];
                if (t0 + XPB == TT) hfinal[j] = hs[XPB - 1];
                if (g + 1 < CHUNK / XPB) {
#pragma unroll
                    for (int u = 0; u < XPB; ++u) xpc[u] = xpn[u];
                }
            }
        }
    }
}

__global__ __launch_bounds__(256, 1) void proj15_kernel(
    const float* in, const float* __restrict__ W, const float* __restrict__ bias,
    float* out, int rows_per_wg)
{
    __shared__ uint4 hb[2][32];
    const int tid = threadIdx.x;
    half2_t wp[128];
#pragma unroll 8
    for (int k = 0; k < 128; ++k) {
        float w0 = W[(size_t)(2 * k) * 256 + tid];
        float w1 = W[(size_t)(2 * k + 1) * 256 + tid];
        wp[k] = h2pack(w0, w1);
    }
    const float bj = bias[tid];
    const size_t r0 = (size_t)blockIdx.x * rows_per_wg;
    proj_rows(in + r0 * 256, out + r0 * 256, wp, bj, rows_per_wg, hb, tid);
}

// serial fallback scan
__global__ __launch_bounds__(256, 1) void scan15_kernel(
    const float* __restrict__ W, const float* __restrict__ h_init,
    float* __restrict__ io, float* __restrict__ hfinal)
{
    __shared__ uint4 hb[2][32];
    const int b = blockIdx.x;
    scan_core<0>(W, h_init + b * 256, io + (size_t)b * TT * 256,
                 io + (size_t)b * TT * 256,
                 hfinal ? hfinal + b * 256 : nullptr, nullptr, nullptr, hb,
                 threadIdx.x);
}

__global__ __launch_bounds__(256, 1) void mega15_kernel(
    const float* __restrict__ W0, const float* __restrict__ W1,
    const float* __restrict__ b1v, const float* __restrict__ h0init,
    float* xpA, float* out, int* flags)
{
    __shared__ uint4 hb[2][32];
    const int tid = threadIdx.x;
    const int bid = blockIdx.x;
    int* flagL0 = flags;               // stride 16 ints per batch (64B line)
    int* chunkdone = flags + BB * 16;  // stride NCHUNK ints per batch

    if (bid < BB) {
        const int b = bid;
        scan_core<1>(W0, h0init + b * 256, xpA + (size_t)b * TT * 256,
                     out + (size_t)b * TT * 256, nullptr, &flagL0[b * 16],
                     nullptr, hb, tid);
    } else if (bid >= 3 * BB) {
        const int b = bid - 3 * BB;
        scan_core<2>(W1, h0init + (size_t)(BB + b) * 256,
                     xpA + (size_t)b * TT * 256, out + (size_t)b * TT * 256,
                     out + (size_t)BB * TT * 256 + b * 256, nullptr,
                     &chunkdone[b * NCHUNK], hb, tid);
    } else {
        // ---- proj1 chasers (2 per batch) ----
        const int k = bid - BB;  // 0..63
        const int b = k >> 1;
        const int half = k & 1;

        half2_t wp[128];
#pragma unroll 8
        for (int kk = 0; kk < 128; ++kk) {
            float w0 = W1[(size_t)(2 * kk) * 256 + tid];
            float w1 = W1[(size_t)(2 * kk + 1) * 256 + tid];
            wp[kk] = h2pack(w0, w1);
        }
        const float bj = b1v[tid];

        for (int chunk = half; chunk < NCHUNK; chunk += 2) {
            while (rload(&flagL0[b * 16]) < (chunk + 1) * CHUNK)
                __builtin_amdgcn_s_sleep(1);
            ACQUIRE_FENCE();  // one inv per chunk
            const int tbase = chunk * CHUNK;
            const float* src = out + ((size_t)b * TT + tbase) * 256;  // h0 rows
            float* dst = xpA + ((size_t)b * TT + tbase) * 256;        // xproj1
            proj_rows(src, dst, wp, bj, CHUNK, hb, tid);
            __syncthreads();  // drain vmcnt (dst stores) before release
            if (tid == 0) astore(&chunkdone[b * NCHUNK + chunk], 1);
        }
    }
}

extern "C" void kernel_launch(void* const* d_in, const int* in_sizes, int n_in,
                              void* d_out, int out_size, void* d_ws, size_t ws_size,
                              hipStream_t stream) {
    const float* x  = (const float*)d_in[0];  // [B,T,256]
    const float* h0 = (const float*)d_in[1];  // [2,B,256]
    const float* W0 = (const float*)d_in[2];  // [512,256]
    const float* b0 = (const float*)d_in[3];  // [256]
    const float* W1 = (const float*)d_in[4];  // [512,256]
    const float* b1 = (const float*)d_in[5];  // [256]
    float* out = (float*)d_out;               // [B*T*256] + [B*256]

    const size_t XPA_FLOATS = (size_t)BB * TT * 256;  // 64 MB
    const size_t FLAG_INTS = (size_t)BB * 16 + (size_t)BB * NCHUNK;
    const size_t NEEDED = XPA_FLOATS * 4 + FLAG_INTS * 4;

    if (ws_size >= NEEDED) {
        float* xpA = (float*)d_ws;
        int* flags = (int*)((char*)d_ws + XPA_FLOATS * 4);
        hipMemsetAsync(flags, 0, FLAG_INTS * 4, stream);
        proj15_kernel<<<256, 256, 0, stream>>>(x, W0, b0, xpA, 256);
        mega15_kernel<<<4 * BB, 256, 0, stream>>>(W0, W1, b1, h0, xpA, out, flags);
    } else {
        proj15_kernel<<<256, 256, 0, stream>>>(x, W0, b0, out, 256);
        scan15_kernel<<<BB, 256, 0, stream>>>(W0, h0, out, nullptr);
        proj15_kernel<<<256, 256, 0, stream>>>(out, W1, b1, out, 256);
        scan15_kernel<<<BB, 256, 0, stream>>>(W1, h0 + BB * 256, out, out + XPA_FLOATS);
    }
}

// Round 16
// 1809.283 us; speedup vs baseline: 11.9014x; 11.9014x over previous
//
#include <hip/hip_runtime.h>

// RNN: B=32, T=2048, E=256, H=256, L=2, f32 in/out, f16 dot core.
// Pipeline (r8/r13-proven): proj0 -> ws.A; mega 128 blocks co-resident:
//   blk 0-31   L0 scan -> d_out rows; publish flagL0[b] every CHUNK steps
//   blk 32-95  chasers (2/batch): xproj1 = h0 @ W1x + b1 -> ws.A
//   blk 96-127 L1 scan: wait chunkdone -> d_out rows + final ht
//
// v16 = v15 with the SCRATCH-SPILL bug fixed. r15's "#pragma unroll 8"
// (partial) on the weight-load loops left wp[k] runtime-indexed -> the whole
// array went to SCRATCH (VGPR_Count=56, WRITE_SIZE 1.7GB, 10x slow; rule:
// runtime-indexed arrays can't be register-allocated). Fix: FULL unroll on
// all weight loads (compile-time indices), and weights stored as plain
// unsigned (bit_cast to f16x2 at use — free) to avoid ext-vector regalloc
// quirks. r15 already proved the f16 core's NUMERICS (absmax 0.00390625).
//
// Core: 256 thr/block, lane owns FULL column j=tid. 256-MAC dot = 128
// v_dot2_f32_f16 on packed-f16x2 weights in VGPRs. h in LDS as f16 (512B);
// all lanes read the SAME addresses -> broadcast, conflict-free. No reduce.
// launch_bounds(256,1): 1 wave/SIMD, 512-reg budget, demand ~170.
// Sync (r13-proven): publisher __syncthreads + release store; consumer
// RELAXED poll + one acquire fence per chunk. Scan barrier LDS-only.

typedef _Float16 half2_t __attribute__((ext_vector_type(2)));

#define TT 2048
#define BB 32
#define XPB 8
#define CHUNK 64
#define NCHUNK (TT / CHUNK)  // 32

__device__ __forceinline__ unsigned packw(float lo, float hi) {
    half2_t r;
    r.x = (_Float16)lo;
    r.y = (_Float16)hi;
    return __builtin_bit_cast(unsigned, r);
}

#define LDS_BARRIER() asm volatile("s_waitcnt lgkmcnt(0)\n\ts_barrier" ::: "memory")

__device__ __forceinline__ int rload(int* pf) {
    return __hip_atomic_load(pf, __ATOMIC_RELAXED, __HIP_MEMORY_SCOPE_AGENT);
}
__device__ __forceinline__ void astore(int* pf, int v) {
    __hip_atomic_store(pf, v, __ATOMIC_RELEASE, __HIP_MEMORY_SCOPE_AGENT);
}
#define ACQUIRE_FENCE() __builtin_amdgcn_fence(__ATOMIC_ACQUIRE, "agent")

// r13-proven keep-alive: force the 128 packed weights into arch VGPRs per step
#define KAW8(B)                                                             \
    "+v"(wp[(B)]), "+v"(wp[(B) + 1]), "+v"(wp[(B) + 2]), "+v"(wp[(B) + 3]), \
    "+v"(wp[(B) + 4]), "+v"(wp[(B) + 5]), "+v"(wp[(B) + 6]), "+v"(wp[(B) + 7])
#define KEEPALIVE()                                                  \
    asm volatile("" : KAW8(0), KAW8(8), KAW8(16), KAW8(24));         \
    asm volatile("" : KAW8(32), KAW8(40), KAW8(48), KAW8(56));       \
    asm volatile("" : KAW8(64), KAW8(72), KAW8(80), KAW8(88));       \
    asm volatile("" : KAW8(96), KAW8(104), KAW8(112), KAW8(120));

#define H2(X) __builtin_bit_cast(half2_t, (X))

// full 256-MAC dot for this lane's column; HB = uint4* to 512B f16 h buffer
#define DOT256(HB, Z)                                                      \
    {                                                                      \
        const uint4* hp4_ = (const uint4*)(HB);                            \
        float ac0 = 0.f, ac1 = 0.f, ac2 = 0.f, ac3 = 0.f;                  \
        _Pragma("unroll")                                                  \
        for (int m = 0; m < 32; ++m) {                                     \
            uint4 r_ = hp4_[m];                                            \
            ac0 = __builtin_amdgcn_fdot2(H2(r_.x), H2(wp[4 * m + 0]), ac0, false); \
            ac1 = __builtin_amdgcn_fdot2(H2(r_.y), H2(wp[4 * m + 1]), ac1, false); \
            ac2 = __builtin_amdgcn_fdot2(H2(r_.z), H2(wp[4 * m + 2]), ac2, false); \
            ac3 = __builtin_amdgcn_fdot2(H2(r_.w), H2(wp[4 * m + 3]), ac3, false); \
        }                                                                  \
        Z = (ac0 + ac1) + (ac2 + ac3);                                     \
    }

// load 128 packed weights from W rows [rowbase, rowbase+256) col j — FULL
// unroll (compile-time indices => register-resident; partial unroll was the
// r15 scratch bug)
#define LOAD_WP(Wm, rowbase, j)                                            \
    _Pragma("unroll")                                                      \
    for (int k = 0; k < 128; ++k) {                                        \
        wp[k] = packw((Wm)[(size_t)((rowbase) + 2 * k) * 256 + (j)],       \
                      (Wm)[(size_t)((rowbase) + 2 * k + 1) * 256 + (j)]);  \
    }

// proj rows: out[r][j] = in[r][:] . W[:256][j] + b[j]; rows staged f32->f16
// in double-buffered LDS. In-place safe (stage precedes overwrite; barriers).
__device__ __forceinline__ void proj_rows(
    const float* __restrict__ src, float* __restrict__ dst,
    unsigned (&wp)[128], float bj, int nrows, uint4 (*hb)[32], int tid)
{
    _Float16* st0 = reinterpret_cast<_Float16*>(hb[0]);
    _Float16* st1 = reinterpret_cast<_Float16*>(hb[1]);
    st0[tid] = (_Float16)src[tid];
    __syncthreads();
    for (int r = 0; r < nrows; ++r) {
        _Float16* stn = (r & 1) ? st0 : st1;
        if (r + 1 < nrows) stn[tid] = (_Float16)src[(size_t)(r + 1) * 256 + tid];
        float z;
        DOT256(hb[r & 1], z);
        dst[(size_t)r * 256 + tid] = z + bj;
        __syncthreads();
    }
}

// MODE: 0 = serial, 1 = L0 (publish pubflag), 2 = L1 (wait waitflags)
template <int MODE>
__device__ __forceinline__ void scan_core(
    const float* __restrict__ W, const float* __restrict__ h_init,
    const float* __restrict__ xsrc, float* __restrict__ hdst, float* hfinal,
    int* pubflag, int* waitflags, uint4 (*hb)[32], int tid)
{
    const int j = tid;
    unsigned wp[128];
    LOAD_WP(W, 256, j)

    _Float16* hw0 = reinterpret_cast<_Float16*>(hb[0]);
    _Float16* hw1 = reinterpret_cast<_Float16*>(hb[1]);
    hw0[j] = (_Float16)h_init[j];

    float xpc[XPB], xpn[XPB], hs[XPB];

    auto step = [&](int t, float xp) -> float {
        KEEPALIVE()
        float z;
        DOT256(hb[t & 1], z);
        z += xp;
        const float e = __expf(2.0f * z);
        const float hn = 1.0f - 2.0f / (e + 1.0f);
        _Float16* dstw = ((t + 1) & 1) ? hw1 : hw0;
        dstw[j] = (_Float16)hn;
        LDS_BARRIER();
        return hn;
    };

    if (MODE != 2) {
#pragma unroll
        for (int u = 0; u < XPB; ++u) xpc[u] = xsrc[(size_t)u * 256 + j];
        __syncthreads();
        for (int t0 = 0; t0 < TT; t0 += XPB) {
            const bool more = (t0 + XPB) < TT;
            if (more) {
#pragma unroll
                for (int u = 0; u < XPB; ++u)
                    xpn[u] = xsrc[(size_t)(t0 + XPB + u) * 256 + j];
            }
#pragma unroll
            for (int u = 0; u < XPB; ++u) hs[u] = step(t0 + u, xpc[u]);
#pragma unroll
            for (int u = 0; u < XPB; ++u)
                hdst[(size_t)(t0 + u) * 256 + j] = hs[u];
            if (MODE == 1 && (((t0 + XPB) & (CHUNK - 1)) == 0)) {
                __syncthreads();  // drain vmcnt (h stores) before release
                if (tid == 0) astore(pubflag, t0 + XPB);
            }
            if (more) {
#pragma unroll
                for (int u = 0; u < XPB; ++u) xpc[u] = xpn[u];
            }
        }
        if (MODE == 0 && hfinal != nullptr) hfinal[j] = hs[XPB - 1];
    } else {
        __syncthreads();
        for (int chunk = 0; chunk < NCHUNK; ++chunk) {
            const int tbase = chunk * CHUNK;
            while (rload(&waitflags[chunk]) == 0) __builtin_amdgcn_s_sleep(1);
            ACQUIRE_FENCE();  // one inv per chunk
#pragma unroll
            for (int u = 0; u < XPB; ++u)
                xpc[u] = xsrc[(size_t)(tbase + u) * 256 + j];
            for (int g = 0; g < CHUNK / XPB; ++g) {
                const int t0 = tbase + g * XPB;
                if (g + 1 < CHUNK / XPB) {
#pragma unroll
                    for (int u = 0; u < XPB; ++u)
                        xpn[u] = xsrc[(size_t)(t0 + XPB + u) * 256 + j];
                }
#pragma unroll
                for (int u = 0; u < XPB; ++u) hs[u] = step(t0 + u, xpc[u]);
#pragma unroll
                for (int u = 0; u < XPB; ++u)
                    hdst[(size_t)(t0 + u) * 256 + j] = hs[u];
                if (t0 + XPB == TT) hfinal[j] = hs[XPB - 1];
                if (g + 1 < CHUNK / XPB) {
#pragma unroll
                    for (int u = 0; u < XPB; ++u) xpc[u] = xpn[u];
                }
            }
        }
    }
}

__global__ __launch_bounds__(256, 1) void proj16_kernel(
    const float* in, const float* __restrict__ W, const float* __restrict__ bias,
    float* out, int rows_per_wg)
{
    __shared__ uint4 hb[2][32];
    const int tid = threadIdx.x;
    unsigned wp[128];
    LOAD_WP(W, 0, tid)
    const float bj = bias[tid];
    const size_t r0 = (size_t)blockIdx.x * rows_per_wg;
    proj_rows(in + r0 * 256, out + r0 * 256, wp, bj, rows_per_wg, hb, tid);
}

// serial fallback scan
__global__ __launch_bounds__(256, 1) void scan16_kernel(
    const float* __restrict__ W, const float* __restrict__ h_init,
    float* __restrict__ io, float* __restrict__ hfinal)
{
    __shared__ uint4 hb[2][32];
    const int b = blockIdx.x;
    scan_core<0>(W, h_init + b * 256, io + (size_t)b * TT * 256,
                 io + (size_t)b * TT * 256,
                 hfinal ? hfinal + b * 256 : nullptr, nullptr, nullptr, hb,
                 threadIdx.x);
}

__global__ __launch_bounds__(256, 1) void mega16_kernel(
    const float* __restrict__ W0, const float* __restrict__ W1,
    const float* __restrict__ b1v, const float* __restrict__ h0init,
    float* xpA, float* out, int* flags)
{
    __shared__ uint4 hb[2][32];
    const int tid = threadIdx.x;
    const int bid = blockIdx.x;
    int* flagL0 = flags;               // stride 16 ints per batch (64B line)
    int* chunkdone = flags + BB * 16;  // stride NCHUNK ints per batch

    if (bid < BB) {
        const int b = bid;
        scan_core<1>(W0, h0init + b * 256, xpA + (size_t)b * TT * 256,
                     out + (size_t)b * TT * 256, nullptr, &flagL0[b * 16],
                     nullptr, hb, tid);
    } else if (bid >= 3 * BB) {
        const int b = bid - 3 * BB;
        scan_core<2>(W1, h0init + (size_t)(BB + b) * 256,
                     xpA + (size_t)b * TT * 256, out + (size_t)b * TT * 256,
                     out + (size_t)BB * TT * 256 + b * 256, nullptr,
                     &chunkdone[b * NCHUNK], hb, tid);
    } else {
        // ---- proj1 chasers (2 per batch) ----
        const int k = bid - BB;  // 0..63
        const int b = k >> 1;
        const int half = k & 1;

        unsigned wp[128];
        LOAD_WP(W1, 0, tid)
        const float bj = b1v[tid];

        for (int chunk = half; chunk < NCHUNK; chunk += 2) {
            while (rload(&flagL0[b * 16]) < (chunk + 1) * CHUNK)
                __builtin_amdgcn_s_sleep(1);
            ACQUIRE_FENCE();  // one inv per chunk
            const int tbase = chunk * CHUNK;
            const float* src = out + ((size_t)b * TT + tbase) * 256;  // h0 rows
            float* dst = xpA + ((size_t)b * TT + tbase) * 256;        // xproj1
            proj_rows(src, dst, wp, bj, CHUNK, hb, tid);
            __syncthreads();  // drain vmcnt (dst stores) before release
            if (tid == 0) astore(&chunkdone[b * NCHUNK + chunk], 1);
        }
    }
}

extern "C" void kernel_launch(void* const* d_in, const int* in_sizes, int n_in,
                              void* d_out, int out_size, void* d_ws, size_t ws_size,
                              hipStream_t stream) {
    const float* x  = (const float*)d_in[0];  // [B,T,256]
    const float* h0 = (const float*)d_in[1];  // [2,B,256]
    const float* W0 = (const float*)d_in[2];  // [512,256]
    const float* b0 = (const float*)d_in[3];  // [256]
    const float* W1 = (const float*)d_in[4];  // [512,256]
    const float* b1 = (const float*)d_in[5];  // [256]
    float* out = (float*)d_out;               // [B*T*256] + [B*256]

    const size_t XPA_FLOATS = (size_t)BB * TT * 256;  // 64 MB
    const size_t FLAG_INTS = (size_t)BB * 16 + (size_t)BB * NCHUNK;
    const size_t NEEDED = XPA_FLOATS * 4 + FLAG_INTS * 4;

    if (ws_size >= NEEDED) {
        float* xpA = (float*)d_ws;
        int* flags = (int*)((char*)d_ws + XPA_FLOATS * 4);
        hipMemsetAsync(flags, 0, FLAG_INTS * 4, stream);
        proj16_kernel<<<256, 256, 0, stream>>>(x, W0, b0, xpA, 256);
        mega16_kernel<<<4 * BB, 256, 0, stream>>>(W0, W1, b1, h0, xpA, out, flags);
    } else {
        proj16_kernel<<<256, 256, 0, stream>>>(x, W0, b0, out, 256);
        scan16_kernel<<<BB, 256, 0, stream>>>(W0, h0, out, nullptr);
        proj16_kernel<<<256, 256, 0, stream>>>(out, W1, b1, out, 256);
        scan16_kernel<<<BB, 256, 0, stream>>>(W1, h0 + BB * 256, out, out + XPA_FLOATS);
    }
}

// Round 17
// 1280.206 us; speedup vs baseline: 16.8200x; 1.4133x over previous
//
#include <hip/hip_runtime.h>

// RNN: B=32, T=2048, E=256, H=256, L=2, f32 in/out, f16 dot core.
// Pipeline (r8/r13/r16-proven): proj0 -> ws.A; mega 128 blocks co-resident:
//   blk 0-31   L0 scan -> d_out rows; publish flagL0[b] every CHUNK steps
//   blk 32-95  chasers (2/batch): xproj1 = h0 @ W1x + b1 -> ws.A
//   blk 96-127 L1 scan: wait chunkdone -> d_out rows + final ht
//
// v17 core = SPLIT-REDUCE (replaces r16's full-broadcast core, which was
// LDS-return-bandwidth-bound: every lane read all 512B/step -> 128 b128
// insts/step ~ 1540cy ~ the whole step). New mapping: thread (jg=tid>>2,
// p=tid&3) computes partials for 4 columns {jg+64c, c=0..3} over i-quarter
// [64p,64p+64): reads 8 b128 = 128B/lane (LDS insts 128->32/step), 128 fdot2
// (the VALU floor), then 2 v_add_f32_dpp quad butterflies per column
// (register-only reduce). Lane p finalizes column jg+64p (static select).
// LDS h layout: f16, quarter-stride 144B (i at byte 144*(i>>6)+2*(i&63)) ->
// the 4 p-group read addresses hit disjoint bank groups (conflict-free).
// Weights: 128 packed f16x2 in VGPRs (r16-proven: full unroll + unsigned
// storage + KEEPALIVE => VGPR-resident, no AGPR parking, no scratch).
// Sync (r13-proven): publisher __syncthreads + release store; consumer
// RELAXED poll + one acquire fence per chunk. Scan barrier LDS-only.

typedef _Float16 half2_t __attribute__((ext_vector_type(2)));

#define TT 2048
#define BB 32
#define XPB 8
#define CHUNK 64
#define NCHUNK (TT / CHUNK)  // 32

__device__ __forceinline__ unsigned packw(float lo, float hi) {
    half2_t r;
    r.x = (_Float16)lo;
    r.y = (_Float16)hi;
    return __builtin_bit_cast(unsigned, r);
}
#define H2(X) __builtin_bit_cast(half2_t, (X))

#define LDS_BARRIER() asm volatile("s_waitcnt lgkmcnt(0)\n\ts_barrier" ::: "memory")

__device__ __forceinline__ int rload(int* pf) {
    return __hip_atomic_load(pf, __ATOMIC_RELAXED, __HIP_MEMORY_SCOPE_AGENT);
}
__device__ __forceinline__ void astore(int* pf, int v) {
    __hip_atomic_store(pf, v, __ATOMIC_RELEASE, __HIP_MEMORY_SCOPE_AGENT);
}
#define ACQUIRE_FENCE() __builtin_amdgcn_fence(__ATOMIC_ACQUIRE, "agent")

// r13/r16-proven keep-alive: pin the 128 packed weights in arch VGPRs
#define KAW8(B)                                                             \
    "+v"(wp[(B)]), "+v"(wp[(B) + 1]), "+v"(wp[(B) + 2]), "+v"(wp[(B) + 3]), \
    "+v"(wp[(B) + 4]), "+v"(wp[(B) + 5]), "+v"(wp[(B) + 6]), "+v"(wp[(B) + 7])
#define KEEPALIVE()                                                  \
    asm volatile("" : KAW8(0), KAW8(8), KAW8(16), KAW8(24));         \
    asm volatile("" : KAW8(32), KAW8(40), KAW8(48), KAW8(56));       \
    asm volatile("" : KAW8(64), KAW8(72), KAW8(80), KAW8(88));       \
    asm volatile("" : KAW8(96), KAW8(104), KAW8(112), KAW8(120));

#define FDOT(H, W_, A) A = __builtin_amdgcn_fdot2(H2(H), H2(W_), A, false)
// one h-dword (2 i's, pair index K) against 4 columns
#define FD4(H, K)               \
    FDOT(H, wp[(K)], ac0);      \
    FDOT(H, wp[32 + (K)], ac1); \
    FDOT(H, wp[64 + (K)], ac2); \
    FDOT(H, wp[96 + (K)], ac3);

// partial dot over this lane's i-quarter for its 4 columns.
// Requires in scope: hbq (const uint4* buffer base), p, wp. Declares ac0..3.
#define DOTS()                                                          \
    float ac0 = 0.f, ac1 = 0.f, ac2 = 0.f, ac3 = 0.f;                   \
    {                                                                   \
        const uint4* hp_ = hbq + 9 * p;                                 \
        uint4 q0 = hp_[0], q1 = hp_[1], q2 = hp_[2], q3 = hp_[3];       \
        uint4 q4 = hp_[4], q5 = hp_[5], q6 = hp_[6], q7 = hp_[7];       \
        FD4(q0.x, 0)  FD4(q0.y, 1)  FD4(q0.z, 2)  FD4(q0.w, 3)         \
        FD4(q1.x, 4)  FD4(q1.y, 5)  FD4(q1.z, 6)  FD4(q1.w, 7)         \
        FD4(q2.x, 8)  FD4(q2.y, 9)  FD4(q2.z, 10) FD4(q2.w, 11)        \
        FD4(q3.x, 12) FD4(q3.y, 13) FD4(q3.z, 14) FD4(q3.w, 15)        \
        FD4(q4.x, 16) FD4(q4.y, 17) FD4(q4.z, 18) FD4(q4.w, 19)        \
        FD4(q5.x, 20) FD4(q5.y, 21) FD4(q5.z, 22) FD4(q5.w, 23)        \
        FD4(q6.x, 24) FD4(q6.y, 25) FD4(q6.z, 26) FD4(q6.w, 27)        \
        FD4(q7.x, 28) FD4(q7.y, 29) FD4(q7.z, 30) FD4(q7.w, 31)        \
    }

// quad butterfly: x = sum over the 4 quad lanes (register-only, exact)
#define BFLY(x)                                                              \
    asm("v_add_f32_dpp %0, %0, %0 quad_perm:[1,0,3,2] row_mask:0xf "         \
        "bank_mask:0xf"                                                      \
        : "+v"(x));                                                          \
    asm("v_add_f32_dpp %0, %0, %0 quad_perm:[2,3,0,1] row_mask:0xf "         \
        "bank_mask:0xf"                                                      \
        : "+v"(x));

// load 128 packed weights: column set {jg+64c}, i-quarter [64p,64p+64),
// rows [rowbase,...). FULL unroll (compile-time wp indices — r15 lesson).
#define LOAD_WP4(Wm, rowbase, p_, jg_)                                       \
    _Pragma("unroll")                                                        \
    for (int c = 0; c < 4; ++c) {                                            \
        _Pragma("unroll")                                                    \
        for (int k = 0; k < 32; ++k) {                                       \
            const int col_ = (jg_) + 64 * c;                                 \
            wp[c * 32 + k] =                                                 \
                packw((Wm)[(size_t)((rowbase) + 64 * (p_) + 2 * k) * 256 +   \
                           col_],                                            \
                      (Wm)[(size_t)((rowbase) + 64 * (p_) + 2 * k + 1) * 256 \
                           + col_]);                                         \
        }                                                                    \
    }

// f16 staging index for element i: byte 144*(i>>6) + 2*(i&63)
__device__ __forceinline__ int sidx_of(int i) {
    return 72 * (i >> 6) + (i & 63);
}

// proj rows: dst[r][col] = src[r][:] . W[:256][col] + b[col]
__device__ __forceinline__ void proj_rows(
    const float* __restrict__ src, float* __restrict__ dst,
    unsigned (&wp)[128], float bj, int nrows, uint4 (*hb)[36], int tid,
    int p, int jg, int col)
{
    _Float16* st0 = reinterpret_cast<_Float16*>(hb[0]);
    _Float16* st1 = reinterpret_cast<_Float16*>(hb[1]);
    const int si = sidx_of(tid);
    st0[si] = (_Float16)src[tid];
    __syncthreads();
    for (int r = 0; r < nrows; ++r) {
        KEEPALIVE()
        _Float16* stn = (r & 1) ? st0 : st1;
        if (r + 1 < nrows) stn[si] = (_Float16)src[(size_t)(r + 1) * 256 + tid];
        const uint4* hbq = hb[r & 1];
        DOTS()
        BFLY(ac0) BFLY(ac1) BFLY(ac2) BFLY(ac3)
        float z = (p == 0) ? ac0 : ((p == 1) ? ac1 : ((p == 2) ? ac2 : ac3));
        dst[(size_t)r * 256 + col] = z + bj;
        __syncthreads();
    }
}

// MODE: 0 = serial, 1 = L0 (publish pubflag), 2 = L1 (wait waitflags)
template <int MODE>
__device__ __forceinline__ void scan_core(
    const float* __restrict__ W, const float* __restrict__ h_init,
    const float* __restrict__ xsrc, float* __restrict__ hdst, float* hfinal,
    int* pubflag, int* waitflags, uint4 (*hb)[36], int tid)
{
    const int p = tid & 3;
    const int jg = tid >> 2;
    const int col = jg + 64 * p;

    unsigned wp[128];
    LOAD_WP4(W, 256, p, jg)

    _Float16* hw0 = reinterpret_cast<_Float16*>(hb[0]);
    _Float16* hw1 = reinterpret_cast<_Float16*>(hb[1]);
    hw0[sidx_of(tid)] = (_Float16)h_init[tid];
    const int wsi = 72 * p + jg;  // where this lane's column lives

    float xpc[XPB], xpn[XPB], hs[XPB];

    auto step = [&](int t, float xp) -> float {
        KEEPALIVE()
        const uint4* hbq = hb[t & 1];
        DOTS()
        BFLY(ac0) BFLY(ac1) BFLY(ac2) BFLY(ac3)
        float z = (p == 0) ? ac0 : ((p == 1) ? ac1 : ((p == 2) ? ac2 : ac3));
        z += xp;
        const float e = __expf(2.0f * z);
        const float hn = 1.0f - 2.0f / (e + 1.0f);
        _Float16* dstw = ((t + 1) & 1) ? hw1 : hw0;
        dstw[wsi] = (_Float16)hn;
        LDS_BARRIER();
        return hn;
    };

    if (MODE != 2) {
#pragma unroll
        for (int u = 0; u < XPB; ++u) xpc[u] = xsrc[(size_t)u * 256 + col];
        __syncthreads();
        for (int t0 = 0; t0 < TT; t0 += XPB) {
            const bool more = (t0 + XPB) < TT;
            if (more) {
#pragma unroll
                for (int u = 0; u < XPB; ++u)
                    xpn[u] = xsrc[(size_t)(t0 + XPB + u) * 256 + col];
            }
#pragma unroll
            for (int u = 0; u < XPB; ++u) hs[u] = step(t0 + u, xpc[u]);
#pragma unroll
            for (int u = 0; u < XPB; ++u)
                hdst[(size_t)(t0 + u) * 256 + col] = hs[u];
            if (MODE == 1 && (((t0 + XPB) & (CHUNK - 1)) == 0)) {
                __syncthreads();  // drain vmcnt (h stores) before release
                if (tid == 0) astore(pubflag, t0 + XPB);
            }
            if (more) {
#pragma unroll
                for (int u = 0; u < XPB; ++u) xpc[u] = xpn[u];
            }
        }
        if (MODE == 0 && hfinal != nullptr) hfinal[col] = hs[XPB - 1];
    } else {
        __syncthreads();
        for (int chunk = 0; chunk < NCHUNK; ++chunk) {
            const int tbase = chunk * CHUNK;
            while (rload(&waitflags[chunk]) == 0) __builtin_amdgcn_s_sleep(1);
            ACQUIRE_FENCE();  // one inv per chunk
#pragma unroll
            for (int u = 0; u < XPB; ++u)
                xpc[u] = xsrc[(size_t)(tbase + u) * 256 + col];
            for (int g = 0; g < CHUNK / XPB; ++g) {
                const int t0 = tbase + g * XPB;
                if (g + 1 < CHUNK / XPB) {
#pragma unroll
                    for (int u = 0; u < XPB; ++u)
                        xpn[u] = xsrc[(size_t)(t0 + XPB + u) * 256 + col];
                }
#pragma unroll
                for (int u = 0; u < XPB; ++u) hs[u] = step(t0 + u, xpc[u]);
#pragma unroll
                for (int u = 0; u < XPB; ++u)
                    hdst[(size_t)(t0 + u) * 256 + col] = hs[u];
                if (t0 + XPB == TT) hfinal[col] = hs[XPB - 1];
                if (g + 1 < CHUNK / XPB) {
#pragma unroll
                    for (int u = 0; u < XPB; ++u) xpc[u] = xpn[u];
                }
            }
        }
    }
}

__global__ __launch_bounds__(256, 1) void proj17_kernel(
    const float* in, const float* __restrict__ W, const float* __restrict__ bias,
    float* out, int rows_per_wg)
{
    __shared__ uint4 hb[2][36];
    const int tid = threadIdx.x;
    const int p = tid & 3;
    const int jg = tid >> 2;
    const int col = jg + 64 * p;
    unsigned wp[128];
    LOAD_WP4(W, 0, p, jg)
    const float bj = bias[col];
    const size_t r0 = (size_t)blockIdx.x * rows_per_wg;
    proj_rows(in + r0 * 256, out + r0 * 256, wp, bj, rows_per_wg, hb, tid, p,
              jg, col);
}

// serial fallback scan
__global__ __launch_bounds__(256, 1) void scan17_kernel(
    const float* __restrict__ W, const float* __restrict__ h_init,
    float* __restrict__ io, float* __restrict__ hfinal)
{
    __shared__ uint4 hb[2][36];
    const int b = blockIdx.x;
    scan_core<0>(W, h_init + b * 256, io + (size_t)b * TT * 256,
                 io + (size_t)b * TT * 256,
                 hfinal ? hfinal + b * 256 : nullptr, nullptr, nullptr, hb,
                 threadIdx.x);
}

__global__ __launch_bounds__(256, 1) void mega17_kernel(
    const float* __restrict__ W0, const float* __restrict__ W1,
    const float* __restrict__ b1v, const float* __restrict__ h0init,
    float* xpA, float* out, int* flags)
{
    __shared__ uint4 hb[2][36];
    const int tid = threadIdx.x;
    const int bid = blockIdx.x;
    int* flagL0 = flags;               // stride 16 ints per batch (64B line)
    int* chunkdone = flags + BB * 16;  // stride NCHUNK ints per batch

    if (bid < BB) {
        const int b = bid;
        scan_core<1>(W0, h0init + b * 256, xpA + (size_t)b * TT * 256,
                     out + (size_t)b * TT * 256, nullptr, &flagL0[b * 16],
                     nullptr, hb, tid);
    } else if (bid >= 3 * BB) {
        const int b = bid - 3 * BB;
        scan_core<2>(W1, h0init + (size_t)(BB + b) * 256,
                     xpA + (size_t)b * TT * 256, out + (size_t)b * TT * 256,
                     out + (size_t)BB * TT * 256 + b * 256, nullptr,
                     &chunkdone[b * NCHUNK], hb, tid);
    } else {
        // ---- proj1 chasers (2 per batch) ----
        const int k = bid - BB;  // 0..63
        const int b = k >> 1;
        const int half = k & 1;
        const int p = tid & 3;
        const int jg = tid >> 2;
        const int col = jg + 64 * p;

        unsigned wp[128];
        LOAD_WP4(W1, 0, p, jg)
        const float bj = b1v[col];

        for (int chunk = half; chunk < NCHUNK; chunk += 2) {
            while (rload(&flagL0[b * 16]) < (chunk + 1) * CHUNK)
                __builtin_amdgcn_s_sleep(1);
            ACQUIRE_FENCE();  // one inv per chunk
            const int tbase = chunk * CHUNK;
            const float* src = out + ((size_t)b * TT + tbase) * 256;  // h0 rows
            float* dst = xpA + ((size_t)b * TT + tbase) * 256;        // xproj1
            proj_rows(src, dst, wp, bj, CHUNK, hb, tid, p, jg, col);
            __syncthreads();  // drain vmcnt (dst stores) before release
            if (tid == 0) astore(&chunkdone[b * NCHUNK + chunk], 1);
        }
    }
}

extern "C" void kernel_launch(void* const* d_in, const int* in_sizes, int n_in,
                              void* d_out, int out_size, void* d_ws, size_t ws_size,
                              hipStream_t stream) {
    const float* x  = (const float*)d_in[0];  // [B,T,256]
    const float* h0 = (const float*)d_in[1];  // [2,B,256]
    const float* W0 = (const float*)d_in[2];  // [512,256]
    const float* b0 = (const float*)d_in[3];  // [256]
    const float* W1 = (const float*)d_in[4];  // [512,256]
    const float* b1 = (const float*)d_in[5];  // [256]
    float* out = (float*)d_out;               // [B*T*256] + [B*256]

    const size_t XPA_FLOATS = (size_t)BB * TT * 256;  // 64 MB
    const size_t FLAG_INTS = (size_t)BB * 16 + (size_t)BB * NCHUNK;
    const size_t NEEDED = XPA_FLOATS * 4 + FLAG_INTS * 4;

    if (ws_size >= NEEDED) {
        float* xpA = (float*)d_ws;
        int* flags = (int*)((char*)d_ws + XPA_FLOATS * 4);
        hipMemsetAsync(flags, 0, FLAG_INTS * 4, stream);
        proj17_kernel<<<256, 256, 0, stream>>>(x, W0, b0, xpA, 256);
        mega17_kernel<<<4 * BB, 256, 0, stream>>>(W0, W1, b1, h0, xpA, out, flags);
    } else {
        proj17_kernel<<<256, 256, 0, stream>>>(x, W0, b0, out, 256);
        scan17_kernel<<<BB, 256, 0, stream>>>(W0, h0, out, nullptr);
        proj17_kernel<<<256, 256, 0, stream>>>(out, W1, b1, out, 256);
        scan17_kernel<<<BB, 256, 0, stream>>>(W1, h0 + BB * 256, out, out + XPA_FLOATS);
    }
}